// Round 6
// baseline (684.658 us; speedup 1.0000x reference)
//
#include <hip/hip_runtime.h>
#include <hip/hip_bf16.h>

#define BATCH 512
#define TIN   256
#define TOUT  128
#define VOC   256
#define NZ    1024
#define EHID  64
#define DHID  128
#define SDIM  32

typedef __attribute__((ext_vector_type(8))) short bf16x8;
typedef __attribute__((ext_vector_type(4))) float f32x4;

__device__ __forceinline__ float bf2f(unsigned short u) {
  return __uint_as_float(((unsigned)u) << 16);
}
__device__ __forceinline__ unsigned short f2bf(float f) {
  unsigned u = __float_as_uint(f);
  u = u + 0x7FFFu + ((u >> 16) & 1u);
  return (unsigned short)(u >> 16);
}
__device__ __forceinline__ float sigf(float x) { return 1.0f / (1.0f + __expf(-x)); }
__device__ __forceinline__ float tanh_(float x) { return 1.0f - 2.0f / (1.0f + __expf(2.0f * x)); }

__device__ __forceinline__ bf16x8 pack8(float4 a, float4 b) {
  bf16x8 r;
  r[0] = (short)f2bf(a.x); r[1] = (short)f2bf(a.y);
  r[2] = (short)f2bf(a.z); r[3] = (short)f2bf(a.w);
  r[4] = (short)f2bf(b.x); r[5] = (short)f2bf(b.y);
  r[6] = (short)f2bf(b.z); r[7] = (short)f2bf(b.w);
  return r;
}

// ---------------------------------------------------------------------------
// Prep: coalesced tiled transposes via LDS.
//  blk 0..63   : WxT[v][g]   = enc_Wih[g][v] + enc_b[g]     (256x256)
//  blk 64..191 : WdecT[v][g] = dec_Wih[g][v] + dec_b[g]     (256x512)
//  blk 192..223: WdT[k][v]   = out_W[v][k]                  (128x256)
// ---------------------------------------------------------------------------
__global__ __launch_bounds__(256) void k_prep(
    const float* __restrict__ enc_Wih, const float* __restrict__ enc_b,
    const float* __restrict__ dec_Wih, const float* __restrict__ dec_b,
    const float* __restrict__ out_W,
    float* __restrict__ WxT, float* __restrict__ WdecT, float* __restrict__ WdT) {
  __shared__ float T[32][36];
  int blk = blockIdx.x, tid = threadIdx.x;
  int r = tid >> 3, c = (tid & 7) * 4;
  if (blk < 64) {
    int g0 = (blk >> 3) * 32, v0 = (blk & 7) * 32;
    float4 v = *(const float4*)(enc_Wih + (size_t)(g0 + r) * (VOC + NZ) + v0 + c);
    float bias = enc_b[g0 + r];
    T[c + 0][r] = v.x + bias; T[c + 1][r] = v.y + bias;
    T[c + 2][r] = v.z + bias; T[c + 3][r] = v.w + bias;
    __syncthreads();
    *(float4*)(WxT + (size_t)(v0 + r) * 256 + g0 + c) = *(const float4*)&T[r][c];
  } else if (blk < 192) {
    int q = blk - 64;
    int g0 = (q >> 3) * 32, v0 = (q & 7) * 32;
    float4 v = *(const float4*)(dec_Wih + (size_t)(g0 + r) * VOC + v0 + c);
    float bias = dec_b[g0 + r];
    T[c + 0][r] = v.x + bias; T[c + 1][r] = v.y + bias;
    T[c + 2][r] = v.z + bias; T[c + 3][r] = v.w + bias;
    __syncthreads();
    *(float4*)(WdecT + (size_t)(v0 + r) * 512 + g0 + c) = *(const float4*)&T[r][c];
  } else {
    int q = blk - 192;
    int v0 = (q >> 2) * 32, k0 = (q & 3) * 32;
    float4 v = *(const float4*)(out_W + (size_t)(v0 + r) * (DHID + SDIM) + k0 + c);
    T[c + 0][r] = v.x; T[c + 1][r] = v.y; T[c + 2][r] = v.z; T[c + 3][r] = v.w;
    __syncthreads();
    *(float4*)(WdT + (size_t)(k0 + r) * 256 + v0 + c) = *(const float4*)&T[r][c];
  }
}

// ---------------------------------------------------------------------------
// One-hot (f32) -> index via wave min-reduce. One wave per position.
// ---------------------------------------------------------------------------
__global__ void k_findidx(const float* __restrict__ src, int n_pos,
                          int* __restrict__ out) {
  int pos = blockIdx.x * 4 + (threadIdx.x >> 6);
  int lane = threadIdx.x & 63;
  if (pos >= n_pos) return;
  float4 v = ((const float4*)src)[(size_t)pos * 64 + lane];
  int comp = v.x > 0.5f ? 0 : (v.y > 0.5f ? 1 : (v.z > 0.5f ? 2 : 3));
  bool hit = (v.x > 0.5f) || (v.y > 0.5f) || (v.z > 0.5f) || (v.w > 0.5f);
  int cand = hit ? lane * 4 + comp : (1 << 30);
#pragma unroll
  for (int off = 32; off > 0; off >>= 1) {
    int o = __shfl_xor(cand, off);
    cand = cand < o ? cand : o;
  }
  if (lane == 0) out[pos] = cand < VOC ? cand : VOC - 1;
}

// ---------------------------------------------------------------------------
// gxc[b][g] = zia[b] . Wz[g]  — tiled 32x32 GEMM, grid (16,8).
// ---------------------------------------------------------------------------
__global__ __launch_bounds__(256) void k_gx_const(
    const float* __restrict__ zia, const float* __restrict__ enc_Wih,
    float* __restrict__ gxc) {
  __shared__ float As[32][36], Bs[32][36];
  int b0 = blockIdx.x * 32, g0 = blockIdx.y * 32;
  int tid = threadIdx.x;
  int ldr = tid >> 3, ldc = (tid & 7) * 4;
  int tx = tid & 15, ty = tid >> 4;
  float a00 = 0.f, a01 = 0.f, a10 = 0.f, a11 = 0.f;
  for (int kc = 0; kc < NZ; kc += 32) {
    float4 av = *(const float4*)(zia + (size_t)(b0 + ldr) * NZ + kc + ldc);
    float4 bv = *(const float4*)(enc_Wih + (size_t)(g0 + ldr) * (VOC + NZ) + VOC + kc + ldc);
    __syncthreads();
    As[ldc + 0][ldr] = av.x; As[ldc + 1][ldr] = av.y;
    As[ldc + 2][ldr] = av.z; As[ldc + 3][ldr] = av.w;
    Bs[ldc + 0][ldr] = bv.x; Bs[ldc + 1][ldr] = bv.y;
    Bs[ldc + 2][ldr] = bv.z; Bs[ldc + 3][ldr] = bv.w;
    __syncthreads();
#pragma unroll
    for (int k = 0; k < 32; ++k) {
      float x0 = As[k][tx * 2], x1 = As[k][tx * 2 + 1];
      float y0 = Bs[k][ty * 2], y1 = Bs[k][ty * 2 + 1];
      a00 += x0 * y0; a01 += x0 * y1; a10 += x1 * y0; a11 += x1 * y1;
    }
  }
  float* o = gxc + (size_t)(b0 + tx * 2) * 256 + g0 + ty * 2;
  o[0] = a00; o[1] = a01; o[256] = a10; o[257] = a11;
}

// ---------------------------------------------------------------------------
// Encoder LSTM scan (MFMA, chunked LDS gx staging — NO vmem in step loop).
// 128 blocks x 256 thr (4 waves). 4 batches at A-rows {0,4,8,12}.
// ---------------------------------------------------------------------------
#define ESTR 72
#define ECH  16
__global__ __launch_bounds__(256) void k_enc_scan(
    const float* __restrict__ enc_Whh, const float* __restrict__ WxT,
    const float* __restrict__ gxc, const int* __restrict__ enc_idx,
    float* __restrict__ h_enc) {
  __shared__ unsigned short hA[2][16 * ESTR];   // 4608 B
  __shared__ unsigned short gxs[ECH * 4 * 256]; // 32 KB  [tt][b][j*4+ty] bf16
  __shared__ int idx_s[4 * TIN];                // 4 KB
  int b0 = blockIdx.x * 4, tid = threadIdx.x;
  int w = tid >> 6, lane = tid & 63, n = lane & 15, q = lane >> 4;
  int j = w * 16 + n;

  bf16x8 Bf[4][2];
#pragma unroll
  for (int ty = 0; ty < 4; ++ty)
#pragma unroll
    for (int kb = 0; kb < 2; ++kb) {
      const float* s = enc_Whh + (size_t)(ty * 64 + j) * EHID + kb * 32 + q * 8;
      Bf[ty][kb] = pack8(*(const float4*)s, *(const float4*)(s + 4));
    }
  float gc[4];
#pragma unroll
  for (int ty = 0; ty < 4; ++ty) gc[ty] = gxc[(size_t)(b0 + q) * 256 + ty * 64 + j];
  for (int i = tid; i < 16 * ESTR; i += 256) { hA[0][i] = 0; hA[1][i] = 0; }
  for (int i = tid; i < 4 * TIN; i += 256)
    idx_s[i] = enc_idx[(size_t)(b0 + (i >> 8)) * TIN + (i & 255)];
  __syncthreads();

  float c0 = 0.f, h = 0.f;
  for (int tc = 0; tc < TIN; tc += ECH) {
    // gather phase: 64 rows (tt,b), 16 per wave; coalesced 1KB row loads
    for (int rr = 0; rr < 16; ++rr) {
      int rowid = w * 16 + rr;
      int tt = rowid >> 2, b = rowid & 3;
      int idx = idx_s[b * TIN + tc + tt];
      float4 v = *(const float4*)(WxT + (size_t)idx * 256 + lane * 4);
      unsigned short* dst = gxs + ((tt * 4 + b) << 8);
      int g0 = lane * 4;
      int ty = g0 >> 6;
      dst[((g0 + 0) & 63) * 4 + ty] = f2bf(v.x);
      dst[((g0 + 1) & 63) * 4 + ty] = f2bf(v.y);
      dst[((g0 + 2) & 63) * 4 + ty] = f2bf(v.z);
      dst[((g0 + 3) & 63) * 4 + ty] = f2bf(v.w);
    }
    __syncthreads();
    for (int tt = 0; tt < ECH; ++tt) {
      int t = tc + tt;
      const unsigned short* cur = hA[t & 1];
      bf16x8 a[2];
#pragma unroll
      for (int kb = 0; kb < 2; ++kb)
        a[kb] = *(const bf16x8*)(cur + n * ESTR + kb * 32 + q * 8);
      ushort4 gx4 = *(const ushort4*)(gxs + ((tt * 4 + q) << 8) + j * 4);
      f32x4 zz[4];
#pragma unroll
      for (int ty = 0; ty < 4; ++ty) {
        f32x4 z;
        z[0] = bf2f(((const unsigned short*)&gx4)[ty]) + gc[ty];
        z[1] = 0.f; z[2] = 0.f; z[3] = 0.f;
        z = __builtin_amdgcn_mfma_f32_16x16x32_bf16(a[0], Bf[ty][0], z, 0, 0, 0);
        z = __builtin_amdgcn_mfma_f32_16x16x32_bf16(a[1], Bf[ty][1], z, 0, 0, 0);
        zz[ty] = z;
      }
      float gi = zz[0][0], gf = zz[1][0], gg = zz[2][0], go = zz[3][0];
      c0 = sigf(gf) * c0 + sigf(gi) * tanh_(gg);
      h = sigf(go) * tanh_(c0);
      hA[(t + 1) & 1][(q * 4) * ESTR + j] = f2bf(h);
      __syncthreads();
    }
  }
  h_enc[(size_t)(b0 + q) * EHID + j] = h;
}

// ---------------------------------------------------------------------------
// sg -> fortza_new (f32, d_out tail) and fout[b][v] = out_b[v] + fn.Wf[v].
// ---------------------------------------------------------------------------
__global__ __launch_bounds__(256) void k_sg_fortza(
    const float* __restrict__ h_enc, const float* __restrict__ fortza,
    const float* __restrict__ sg_W, const float* __restrict__ sg_b,
    const float* __restrict__ out_W, const float* __restrict__ out_b,
    float* __restrict__ out_fortza, float* __restrict__ fout) {
  __shared__ float hf[EHID], fz[SDIM], sg_s[2 * SDIM], fn[SDIM];
  int b = blockIdx.x, tid = threadIdx.x;
  if (tid < EHID) hf[tid] = h_enc[b * EHID + tid];
  if (tid >= EHID && tid < EHID + SDIM)
    fz[tid - EHID] = fortza[(size_t)b * SDIM + (tid - EHID)];
  __syncthreads();
  if (tid < 2 * SDIM) {
    float acc = sg_b[tid];
    const float* row = sg_W + (size_t)tid * (EHID + SDIM);
    for (int k = 0; k < EHID; ++k) acc += hf[k] * row[k];
    for (int jj = 0; jj < SDIM; ++jj) acc += fz[jj] * row[EHID + jj];
    sg_s[tid] = acc;
  }
  __syncthreads();
  if (tid < SDIM) {
    float gate = sigf(sg_s[tid]);
    float upd = tanh_(sg_s[SDIM + tid]);
    float v = gate * fz[tid] + (1.0f - gate) * upd;
    fn[tid] = v;
    out_fortza[(size_t)b * SDIM + tid] = v;
  }
  __syncthreads();
  {
    float acc = out_b[tid];
    const float* row = out_W + (size_t)tid * (DHID + SDIM) + DHID;
    for (int jj = 0; jj < SDIM; ++jj) acc += fn[jj] * row[jj];
    fout[b * VOC + tid] = acc;
  }
}

// ---------------------------------------------------------------------------
// dh0[b][v] = tanh([h_enc|zia] . Wc_W[v] + Wc_b[v]) — tiled GEMM, grid (16,4).
// ---------------------------------------------------------------------------
__global__ __launch_bounds__(256) void k_dh0(
    const float* __restrict__ h_enc, const float* __restrict__ zia,
    const float* __restrict__ Wc_W, const float* __restrict__ Wc_b,
    float* __restrict__ dh0) {
  __shared__ float As[32][36], Bs[32][36];
  int b0 = blockIdx.x * 32, v0 = blockIdx.y * 32;
  int tid = threadIdx.x;
  int ldr = tid >> 3, ldc = (tid & 7) * 4;
  int tx = tid & 15, ty = tid >> 4;
  float a00 = 0.f, a01 = 0.f, a10 = 0.f, a11 = 0.f;
  for (int kc = 0; kc < EHID + NZ; kc += 32) {
    float4 av;
    if (kc < EHID)
      av = *(const float4*)(h_enc + (size_t)(b0 + ldr) * EHID + kc + ldc);
    else
      av = *(const float4*)(zia + (size_t)(b0 + ldr) * NZ + (kc - EHID) + ldc);
    float4 bv = *(const float4*)(Wc_W + (size_t)(v0 + ldr) * (EHID + NZ) + kc + ldc);
    __syncthreads();
    As[ldc + 0][ldr] = av.x; As[ldc + 1][ldr] = av.y;
    As[ldc + 2][ldr] = av.z; As[ldc + 3][ldr] = av.w;
    Bs[ldc + 0][ldr] = bv.x; Bs[ldc + 1][ldr] = bv.y;
    Bs[ldc + 2][ldr] = bv.z; Bs[ldc + 3][ldr] = bv.w;
    __syncthreads();
#pragma unroll
    for (int k = 0; k < 32; ++k) {
      float x0 = As[k][tx * 2], x1 = As[k][tx * 2 + 1];
      float y0 = Bs[k][ty * 2], y1 = Bs[k][ty * 2 + 1];
      a00 += x0 * y0; a01 += x0 * y1; a10 += x1 * y0; a11 += x1 * y1;
    }
  }
  float bb0 = Wc_b[v0 + ty * 2], bb1 = Wc_b[v0 + ty * 2 + 1];
  float* o = dh0 + (size_t)(b0 + tx * 2) * DHID + v0 + ty * 2;
  o[0] = tanh_(a00 + bb0); o[1] = tanh_(a01 + bb1);
  o[DHID] = tanh_(a10 + bb0); o[DHID + 1] = tanh_(a11 + bb1);
}

// ---------------------------------------------------------------------------
// Decoder LSTM scan (MFMA, chunked LDS gx staging + chunked dhs dump).
// 128 blocks x 512 thr (8 waves). NO vmem in step loop.
// ---------------------------------------------------------------------------
#define DSTR 136
#define DCH  8
__global__ __launch_bounds__(512) void k_dec_scan(
    const float* __restrict__ dec_Whh, const float* __restrict__ WdecT,
    const int* __restrict__ dec_idx, const float* __restrict__ dh0,
    unsigned short* __restrict__ dhs) {
  __shared__ unsigned short hA[2][16 * DSTR];    // 8704 B
  __shared__ unsigned short gxs[DCH * 4 * 512];  // 32 KB [tt][b][j*4+ty]
  __shared__ unsigned short hH[DCH * 4 * DHID];  // 8 KB  [tt*4+b][j]
  __shared__ int idx_s[4 * TOUT];                // 2 KB
  int b0 = blockIdx.x * 4, tid = threadIdx.x;
  int w = tid >> 6, lane = tid & 63, n = lane & 15, q = lane >> 4;
  int j = w * 16 + n;

  bf16x8 Bf[4][4];
#pragma unroll
  for (int ty = 0; ty < 4; ++ty)
#pragma unroll
    for (int kb = 0; kb < 4; ++kb) {
      const float* s = dec_Whh + (size_t)(ty * 128 + j) * DHID + kb * 32 + q * 8;
      Bf[ty][kb] = pack8(*(const float4*)s, *(const float4*)(s + 4));
    }
  for (int i = tid; i < 16 * DSTR; i += 512) {
    int m = i / DSTR, k = i - m * DSTR;
    float v = (k < DHID && (m & 3) == 0) ? dh0[(size_t)(b0 + (m >> 2)) * DHID + k] : 0.f;
    hA[0][i] = f2bf(v);
    hA[1][i] = 0;
  }
  for (int i = tid; i < 4 * TOUT; i += 512)
    idx_s[i] = dec_idx[(size_t)(b0 + (i >> 7)) * TOUT + (i & 127)];
  __syncthreads();

  float c0 = 0.f;
  for (int tc = 0; tc < TOUT; tc += DCH) {
    // dump previous chunk's h history to global
    if (tc > 0) {
      int tp = tc - DCH;
      for (int u = tid; u < DCH * 4 * DHID / 4; u += 512) {
        int jj = (u & 31) * 4;
        int rowid = u >> 5;
        int tt = rowid >> 2, b = rowid & 3;
        *(ushort4*)(dhs + ((size_t)(tp + tt) * BATCH + (b0 + b)) * DHID + jj) =
            *(const ushort4*)(hH + (rowid << 7) + jj);
      }
    }
    // gather gx: 32 rows (tt,b), 4 per wave, 2KB/row coalesced
    for (int rr = 0; rr < 4; ++rr) {
      int rowid = w * 4 + rr;
      int tt = rowid >> 2, b = rowid & 3;
      int idx = idx_s[b * TOUT + tc + tt];
      const float* srow = WdecT + (size_t)idx * 512;
      unsigned short* dst = gxs + ((tt * 4 + b) << 9);
#pragma unroll
      for (int hs = 0; hs < 2; ++hs) {
        float4 v = *(const float4*)(srow + hs * 256 + lane * 4);
        int g0 = hs * 256 + lane * 4;
        int ty = g0 >> 7;
        dst[((g0 + 0) & 127) * 4 + ty] = f2bf(v.x);
        dst[((g0 + 1) & 127) * 4 + ty] = f2bf(v.y);
        dst[((g0 + 2) & 127) * 4 + ty] = f2bf(v.z);
        dst[((g0 + 3) & 127) * 4 + ty] = f2bf(v.w);
      }
    }
    __syncthreads();
    for (int tt = 0; tt < DCH; ++tt) {
      int t = tc + tt;
      const unsigned short* cur = hA[t & 1];
      bf16x8 a[4];
#pragma unroll
      for (int kb = 0; kb < 4; ++kb)
        a[kb] = *(const bf16x8*)(cur + n * DSTR + kb * 32 + q * 8);
      ushort4 gx4 = *(const ushort4*)(gxs + ((tt * 4 + q) << 9) + j * 4);
      f32x4 zz[4];
#pragma unroll
      for (int ty = 0; ty < 4; ++ty) {
        f32x4 z;
        z[0] = bf2f(((const unsigned short*)&gx4)[ty]);
        z[1] = 0.f; z[2] = 0.f; z[3] = 0.f;
#pragma unroll
        for (int kb = 0; kb < 4; ++kb)
          z = __builtin_amdgcn_mfma_f32_16x16x32_bf16(a[kb], Bf[ty][kb], z, 0, 0, 0);
        zz[ty] = z;
      }
      float gi = zz[0][0], gf = zz[1][0], gg = zz[2][0], go = zz[3][0];
      c0 = sigf(gf) * c0 + sigf(gi) * tanh_(gg);
      float h = sigf(go) * tanh_(c0);
      unsigned short hb = f2bf(h);
      hA[(t + 1) & 1][(q * 4) * DSTR + j] = hb;
      hH[((tt * 4 + q) << 7) + j] = hb;
      __syncthreads();
    }
  }
  // final dump
  {
    int tp = TOUT - DCH;
    for (int u = tid; u < DCH * 4 * DHID / 4; u += 512) {
      int jj = (u & 31) * 4;
      int rowid = u >> 5;
      int tt = rowid >> 2, b = rowid & 3;
      *(ushort4*)(dhs + ((size_t)(tp + tt) * BATCH + (b0 + b)) * DHID + jj) =
          *(const ushort4*)(hH + (rowid << 7) + jj);
    }
  }
}

// ---------------------------------------------------------------------------
// logits[b][t][v] = dhs[t][b][:] . WdT[:][v] + fout[b][v];  f32 store.
// ---------------------------------------------------------------------------
__global__ __launch_bounds__(256) void k_logits(const unsigned short* __restrict__ dhs,
                                                const float* __restrict__ WdT,
                                                const float* __restrict__ fout,
                                                float* __restrict__ out) {
  __shared__ float s[DHID * 64];  // k-major: s[k*64 + m]
  int r0 = blockIdx.x * 64;
  int t = r0 / BATCH;
  int b0 = r0 % BATCH;
  int tid = threadIdx.x;
  for (int i = tid; i < 64 * DHID; i += 256) {
    int m = i >> 7;
    int k = i & 127;
    s[k * 64 + m] = bf2f(dhs[(size_t)(r0 + m) * DHID + k]);
  }
  __syncthreads();
  int v4 = tid & 63;
  int mg = tid >> 6;
  float4 acc[16];
#pragma unroll
  for (int m = 0; m < 16; ++m) acc[m] = make_float4(0.f, 0.f, 0.f, 0.f);
  for (int k = 0; k < DHID; ++k) {
    float4 wv = ((const float4*)(WdT + k * 256))[v4];
    const float4* sk = (const float4*)(s + k * 64 + mg * 16);
#pragma unroll
    for (int jj = 0; jj < 4; ++jj) {
      float4 h4 = sk[jj];
      acc[jj * 4 + 0].x += h4.x * wv.x; acc[jj * 4 + 0].y += h4.x * wv.y;
      acc[jj * 4 + 0].z += h4.x * wv.z; acc[jj * 4 + 0].w += h4.x * wv.w;
      acc[jj * 4 + 1].x += h4.y * wv.x; acc[jj * 4 + 1].y += h4.y * wv.y;
      acc[jj * 4 + 1].z += h4.y * wv.z; acc[jj * 4 + 1].w += h4.y * wv.w;
      acc[jj * 4 + 2].x += h4.z * wv.x; acc[jj * 4 + 2].y += h4.z * wv.y;
      acc[jj * 4 + 2].z += h4.z * wv.z; acc[jj * 4 + 2].w += h4.z * wv.w;
      acc[jj * 4 + 3].x += h4.w * wv.x; acc[jj * 4 + 3].y += h4.w * wv.y;
      acc[jj * 4 + 3].z += h4.w * wv.z; acc[jj * 4 + 3].w += h4.w * wv.w;
    }
  }
#pragma unroll
  for (int m = 0; m < 16; ++m) {
    int bb = b0 + mg * 16 + m;
    float4 fo = ((const float4*)(fout + bb * VOC))[v4];
    float4 r;
    r.x = acc[m].x + fo.x;
    r.y = acc[m].y + fo.y;
    r.z = acc[m].z + fo.z;
    r.w = acc[m].w + fo.w;
    ((float4*)(out + ((size_t)bb * TOUT + t) * VOC))[v4] = r;
  }
}

// ---------------------------------------------------------------------------
extern "C" void kernel_launch(void* const* d_in, const int* in_sizes, int n_in,
                              void* d_out, int out_size, void* d_ws, size_t ws_size,
                              hipStream_t stream) {
  const float* inp_onehot = (const float*)d_in[0];
  const float* zia     = (const float*)d_in[1];
  const float* tgt     = (const float*)d_in[2];
  const float* fortza  = (const float*)d_in[3];
  const float* enc_Wih = (const float*)d_in[4];
  const float* enc_Whh = (const float*)d_in[5];
  const float* enc_b   = (const float*)d_in[6];
  const float* sg_W    = (const float*)d_in[7];
  const float* sg_b    = (const float*)d_in[8];
  const float* Wc_W    = (const float*)d_in[9];
  const float* Wc_b    = (const float*)d_in[10];
  const float* dec_Wih = (const float*)d_in[11];
  const float* dec_Whh = (const float*)d_in[12];
  const float* dec_b   = (const float*)d_in[13];
  const float* out_W   = (const float*)d_in[14];
  const float* out_b   = (const float*)d_in[15];
  float* out = (float*)d_out;

  float* ws = (float*)d_ws;
  int* enc_idx  = (int*)d_ws;              // 131072 ints
  int* dec_idx  = enc_idx + BATCH * TIN;   //  65536 ints
  float* WxT    = ws + 196608;             //  65536 f
  float* WdecT  = ws + 262144;             // 131072 f
  float* WdT    = ws + 393216;             //  32768 f
  float* gxc    = ws + 425984;             // 131072 f
  float* h_enc  = ws + 557056;             //  32768 f
  float* dh0    = ws + 589824;             //  65536 f
  float* fout   = ws + 655360;             // 131072 f
  unsigned short* dhs = (unsigned short*)(ws + 786432);  // 8388608 u16; ~19.9 MB

  k_prep<<<224, 256, 0, stream>>>(enc_Wih, enc_b, dec_Wih, dec_b, out_W, WxT, WdecT, WdT);
  k_findidx<<<BATCH * TIN / 4, 256, 0, stream>>>(inp_onehot, BATCH * TIN, enc_idx);
  k_findidx<<<BATCH * TOUT / 4, 256, 0, stream>>>(tgt, BATCH * TOUT, dec_idx);
  k_gx_const<<<dim3(16, 8), 256, 0, stream>>>(zia, enc_Wih, gxc);
  k_enc_scan<<<BATCH / 4, 256, 0, stream>>>(enc_Whh, WxT, gxc, enc_idx, h_enc);
  k_sg_fortza<<<BATCH, 256, 0, stream>>>(h_enc, fortza, sg_W, sg_b, out_W, out_b,
                                         out + (size_t)BATCH * TOUT * VOC, fout);
  k_dh0<<<dim3(16, 4), 256, 0, stream>>>(h_enc, zia, Wc_W, Wc_b, dh0);
  k_dec_scan<<<BATCH / 4, 512, 0, stream>>>(dec_Whh, WdecT, dec_idx, dh0, dhs);
  k_logits<<<TOUT * BATCH / 64, 256, 0, stream>>>(dhs, WdT, fout, out);
}

// Round 7
// 568.552 us; speedup vs baseline: 1.2042x; 1.2042x over previous
//
#include <hip/hip_runtime.h>
#include <hip/hip_bf16.h>

#define BATCH 512
#define TIN   256
#define TOUT  128
#define VOC   256
#define NZ    1024
#define EHID  64
#define DHID  128
#define SDIM  32

typedef __attribute__((ext_vector_type(8))) short bf16x8;
typedef __attribute__((ext_vector_type(4))) float f32x4;

__device__ __forceinline__ float bf2f(unsigned short u) {
  return __uint_as_float(((unsigned)u) << 16);
}
__device__ __forceinline__ unsigned short f2bf(float f) {
  unsigned u = __float_as_uint(f);
  u = u + 0x7FFFu + ((u >> 16) & 1u);
  return (unsigned short)(u >> 16);
}
__device__ __forceinline__ float sigf(float x) { return 1.0f / (1.0f + __expf(-x)); }
__device__ __forceinline__ float tanh_(float x) { return 1.0f - 2.0f / (1.0f + __expf(2.0f * x)); }

__device__ __forceinline__ bf16x8 pack8(float4 a, float4 b) {
  bf16x8 r;
  r[0] = (short)f2bf(a.x); r[1] = (short)f2bf(a.y);
  r[2] = (short)f2bf(a.z); r[3] = (short)f2bf(a.w);
  r[4] = (short)f2bf(b.x); r[5] = (short)f2bf(b.y);
  r[6] = (short)f2bf(b.z); r[7] = (short)f2bf(b.w);
  return r;
}

// ---------------------------------------------------------------------------
// findidx worker: one wave handles one position (256 f32 one-hot row).
// ---------------------------------------------------------------------------
__device__ __forceinline__ void dev_findidx(const float* __restrict__ src,
                                            int pos, int lane,
                                            int* __restrict__ out) {
  float4 v = ((const float4*)src)[(size_t)pos * 64 + lane];
  int comp = v.x > 0.5f ? 0 : (v.y > 0.5f ? 1 : (v.z > 0.5f ? 2 : 3));
  bool hit = (v.x > 0.5f) || (v.y > 0.5f) || (v.z > 0.5f) || (v.w > 0.5f);
  int cand = hit ? lane * 4 + comp : (1 << 30);
#pragma unroll
  for (int off = 32; off > 0; off >>= 1) {
    int o = __shfl_xor(cand, off);
    cand = cand < o ? cand : o;
  }
  if (lane == 0) out[pos] = cand < VOC ? cand : VOC - 1;
}

// ---------------------------------------------------------------------------
// Launch A: WxT prep (blocks 0..63) | gx_const (64..191) | findidx enc (192+).
// ---------------------------------------------------------------------------
__global__ __launch_bounds__(256) void k_pre(
    const float* __restrict__ enc_Wih, const float* __restrict__ enc_b,
    const float* __restrict__ inp_onehot, const float* __restrict__ zia,
    float* __restrict__ WxT, float* __restrict__ gxc, int* __restrict__ enc_idx) {
  int blk = blockIdx.x, tid = threadIdx.x;
  if (blk < 64) {
    __shared__ float T[32][36];
    int r = tid >> 3, c = (tid & 7) * 4;
    int g0 = (blk >> 3) * 32, v0 = (blk & 7) * 32;
    float4 v = *(const float4*)(enc_Wih + (size_t)(g0 + r) * (VOC + NZ) + v0 + c);
    float bias = enc_b[g0 + r];
    T[c + 0][r] = v.x + bias; T[c + 1][r] = v.y + bias;
    T[c + 2][r] = v.z + bias; T[c + 3][r] = v.w + bias;
    __syncthreads();
    *(float4*)(WxT + (size_t)(v0 + r) * 256 + g0 + c) = *(const float4*)&T[r][c];
  } else if (blk < 192) {
    __shared__ float As[32][36], Bs[32][36];
    int q = blk - 64;
    int b0 = (q & 15) * 32, g0 = (q >> 4) * 32;
    int ldr = tid >> 3, ldc = (tid & 7) * 4;
    int tx = tid & 15, ty = tid >> 4;
    float a00 = 0.f, a01 = 0.f, a10 = 0.f, a11 = 0.f;
    for (int kc = 0; kc < NZ; kc += 32) {
      float4 av = *(const float4*)(zia + (size_t)(b0 + ldr) * NZ + kc + ldc);
      float4 bv = *(const float4*)(enc_Wih + (size_t)(g0 + ldr) * (VOC + NZ) + VOC + kc + ldc);
      __syncthreads();
      As[ldc + 0][ldr] = av.x; As[ldc + 1][ldr] = av.y;
      As[ldc + 2][ldr] = av.z; As[ldc + 3][ldr] = av.w;
      Bs[ldc + 0][ldr] = bv.x; Bs[ldc + 1][ldr] = bv.y;
      Bs[ldc + 2][ldr] = bv.z; Bs[ldc + 3][ldr] = bv.w;
      __syncthreads();
#pragma unroll
      for (int k = 0; k < 32; ++k) {
        float x0 = As[k][tx * 2], x1 = As[k][tx * 2 + 1];
        float y0 = Bs[k][ty * 2], y1 = Bs[k][ty * 2 + 1];
        a00 += x0 * y0; a01 += x0 * y1; a10 += x1 * y0; a11 += x1 * y1;
      }
    }
    float* o = gxc + (size_t)(b0 + tx * 2) * 256 + g0 + ty * 2;
    o[0] = a00; o[1] = a01; o[256] = a10; o[257] = a11;
  } else {
    int pos = (blk - 192) * 4 + (tid >> 6);
    if (pos < BATCH * TIN) dev_findidx(inp_onehot, pos, tid & 63, enc_idx);
  }
}

// ---------------------------------------------------------------------------
// Launch B: enc_scan (blocks 0..127, round-5 proven form) | WdecT prep
// (128..255) | WdT prep (256..287) | findidx dec (288+).
// ---------------------------------------------------------------------------
#define ESTR 72
__global__ __launch_bounds__(256) void k_enc_fused(
    const float* __restrict__ enc_Whh, const float* __restrict__ WxT,
    const float* __restrict__ gxc, const int* __restrict__ enc_idx,
    float* __restrict__ h_enc,
    const float* __restrict__ dec_Wih, const float* __restrict__ dec_b,
    const float* __restrict__ out_W, const float* __restrict__ tgt,
    float* __restrict__ WdecT, float* __restrict__ WdT, int* __restrict__ dec_idx) {
  int blk = blockIdx.x, tid = threadIdx.x;
  if (blk < 128) {
    // ---- encoder scan (round-5 form) ----
    __shared__ unsigned short hA[2][16 * ESTR];
    __shared__ int idx_s[4][TIN];
    int b0 = blk * 4;
    int w = tid >> 6, lane = tid & 63, n = lane & 15, quad = lane >> 4;
    int j = w * 16 + n;

    bf16x8 Bf[4][2];
#pragma unroll
    for (int ty = 0; ty < 4; ++ty)
#pragma unroll
      for (int kb = 0; kb < 2; ++kb) {
        const float* s = enc_Whh + (size_t)(ty * 64 + j) * EHID + kb * 32 + quad * 8;
        Bf[ty][kb] = pack8(*(const float4*)s, *(const float4*)(s + 4));
      }
    for (int i = tid; i < 16 * ESTR; i += 256) { hA[0][i] = 0; hA[1][i] = 0; }
    for (int i = tid; i < 4 * TIN; i += 256)
      idx_s[i >> 8][i & 255] = enc_idx[(size_t)(b0 + (i >> 8)) * TIN + (i & 255)];
    float gc[4];
#pragma unroll
    for (int ty = 0; ty < 4; ++ty) gc[ty] = gxc[(size_t)(b0 + quad) * 256 + ty * 64 + j];
    __syncthreads();

    float gx[4];
    {
      int id0 = idx_s[quad][0];
#pragma unroll
      for (int ty = 0; ty < 4; ++ty) gx[ty] = WxT[(size_t)id0 * 256 + ty * 64 + j];
    }
    float c0 = 0.0f, h = 0.0f;
    for (int t = 0; t < TIN; ++t) {
      const unsigned short* cur = hA[t & 1];
      bf16x8 a[2];
#pragma unroll
      for (int kb = 0; kb < 2; ++kb)
        a[kb] = *(const bf16x8*)(cur + n * ESTR + kb * 32 + quad * 8);
      float gxn[4];
      int tn = (t + 1 < TIN) ? t + 1 : t;
      int idn = idx_s[quad][tn];
#pragma unroll
      for (int ty = 0; ty < 4; ++ty) gxn[ty] = WxT[(size_t)idn * 256 + ty * 64 + j];
      f32x4 acc[4];
#pragma unroll
      for (int ty = 0; ty < 4; ++ty) {
        f32x4 z; z[0] = gx[ty] + gc[ty]; z[1] = 0.f; z[2] = 0.f; z[3] = 0.f;
        z = __builtin_amdgcn_mfma_f32_16x16x32_bf16(a[0], Bf[ty][0], z, 0, 0, 0);
        z = __builtin_amdgcn_mfma_f32_16x16x32_bf16(a[1], Bf[ty][1], z, 0, 0, 0);
        acc[ty] = z;
      }
      float gi = acc[0][0], gf = acc[1][0], gg = acc[2][0], go = acc[3][0];
      c0 = sigf(gf) * c0 + sigf(gi) * tanh_(gg);
      h = sigf(go) * tanh_(c0);
      hA[(t + 1) & 1][(quad * 4) * ESTR + j] = f2bf(h);
      gx[0] = gxn[0]; gx[1] = gxn[1]; gx[2] = gxn[2]; gx[3] = gxn[3];
      __syncthreads();
    }
    h_enc[(size_t)(b0 + quad) * EHID + j] = h;
  } else if (blk < 256) {
    __shared__ float T[32][36];
    int q = blk - 128;
    int r = tid >> 3, c = (tid & 7) * 4;
    int g0 = (q >> 3) * 32, v0 = (q & 7) * 32;
    float4 v = *(const float4*)(dec_Wih + (size_t)(g0 + r) * VOC + v0 + c);
    float bias = dec_b[g0 + r];
    T[c + 0][r] = v.x + bias; T[c + 1][r] = v.y + bias;
    T[c + 2][r] = v.z + bias; T[c + 3][r] = v.w + bias;
    __syncthreads();
    *(float4*)(WdecT + (size_t)(v0 + r) * 512 + g0 + c) = *(const float4*)&T[r][c];
  } else if (blk < 288) {
    __shared__ float T2[32][36];
    int q = blk - 256;
    int r = tid >> 3, c = (tid & 7) * 4;
    int v0 = (q >> 2) * 32, k0 = (q & 3) * 32;
    float4 v = *(const float4*)(out_W + (size_t)(v0 + r) * (DHID + SDIM) + k0 + c);
    T2[c + 0][r] = v.x; T2[c + 1][r] = v.y; T2[c + 2][r] = v.z; T2[c + 3][r] = v.w;
    __syncthreads();
    *(float4*)(WdT + (size_t)(k0 + r) * 256 + v0 + c) = *(const float4*)&T2[r][c];
  } else {
    int pos = (blk - 288) * 4 + (tid >> 6);
    if (pos < BATCH * TOUT) dev_findidx(tgt, pos, tid & 63, dec_idx);
  }
}

// ---------------------------------------------------------------------------
// Launch C: sg_fortza (blocks 0..511) | dh0 tiled GEMM (512..575).
// ---------------------------------------------------------------------------
__global__ __launch_bounds__(256) void k_mid(
    const float* __restrict__ h_enc, const float* __restrict__ fortza,
    const float* __restrict__ sg_W, const float* __restrict__ sg_b,
    const float* __restrict__ out_W, const float* __restrict__ out_b,
    const float* __restrict__ zia, const float* __restrict__ Wc_W,
    const float* __restrict__ Wc_b,
    float* __restrict__ out_fortza, float* __restrict__ fout,
    float* __restrict__ dh0) {
  int blk = blockIdx.x, tid = threadIdx.x;
  if (blk < 512) {
    __shared__ float hf[EHID], fz[SDIM], sg_s[2 * SDIM], fn[SDIM];
    int b = blk;
    if (tid < EHID) hf[tid] = h_enc[b * EHID + tid];
    if (tid >= EHID && tid < EHID + SDIM)
      fz[tid - EHID] = fortza[(size_t)b * SDIM + (tid - EHID)];
    __syncthreads();
    if (tid < 2 * SDIM) {
      float acc = sg_b[tid];
      const float* row = sg_W + (size_t)tid * (EHID + SDIM);
      for (int k = 0; k < EHID; ++k) acc += hf[k] * row[k];
      for (int jj = 0; jj < SDIM; ++jj) acc += fz[jj] * row[EHID + jj];
      sg_s[tid] = acc;
    }
    __syncthreads();
    if (tid < SDIM) {
      float gate = sigf(sg_s[tid]);
      float upd = tanh_(sg_s[SDIM + tid]);
      float v = gate * fz[tid] + (1.0f - gate) * upd;
      fn[tid] = v;
      out_fortza[(size_t)b * SDIM + tid] = v;
    }
    __syncthreads();
    {
      float acc = out_b[tid];
      const float* row = out_W + (size_t)tid * (DHID + SDIM) + DHID;
      for (int jj = 0; jj < SDIM; ++jj) acc += fn[jj] * row[jj];
      fout[b * VOC + tid] = acc;
    }
  } else {
    __shared__ float As[32][36], Bs[32][36];
    int q = blk - 512;
    int b0 = (q & 15) * 32, v0 = (q >> 4) * 32;
    int ldr = tid >> 3, ldc = (tid & 7) * 4;
    int tx = tid & 15, ty = tid >> 4;
    float a00 = 0.f, a01 = 0.f, a10 = 0.f, a11 = 0.f;
    for (int kc = 0; kc < EHID + NZ; kc += 32) {
      float4 av;
      if (kc < EHID)
        av = *(const float4*)(h_enc + (size_t)(b0 + ldr) * EHID + kc + ldc);
      else
        av = *(const float4*)(zia + (size_t)(b0 + ldr) * NZ + (kc - EHID) + ldc);
      float4 bv = *(const float4*)(Wc_W + (size_t)(v0 + ldr) * (EHID + NZ) + kc + ldc);
      __syncthreads();
      As[ldc + 0][ldr] = av.x; As[ldc + 1][ldr] = av.y;
      As[ldc + 2][ldr] = av.z; As[ldc + 3][ldr] = av.w;
      Bs[ldc + 0][ldr] = bv.x; Bs[ldc + 1][ldr] = bv.y;
      Bs[ldc + 2][ldr] = bv.z; Bs[ldc + 3][ldr] = bv.w;
      __syncthreads();
#pragma unroll
      for (int k = 0; k < 32; ++k) {
        float x0 = As[k][tx * 2], x1 = As[k][tx * 2 + 1];
        float y0 = Bs[k][ty * 2], y1 = Bs[k][ty * 2 + 1];
        a00 += x0 * y0; a01 += x0 * y1; a10 += x1 * y0; a11 += x1 * y1;
      }
    }
    float bb0 = Wc_b[v0 + ty * 2], bb1 = Wc_b[v0 + ty * 2 + 1];
    float* o = dh0 + (size_t)(b0 + tx * 2) * DHID + v0 + ty * 2;
    o[0] = tanh_(a00 + bb0); o[1] = tanh_(a01 + bb1);
    o[DHID] = tanh_(a10 + bb0); o[DHID + 1] = tanh_(a11 + bb1);
  }
}

// ---------------------------------------------------------------------------
// Decoder LSTM scan (round-5 proven form). 128 blocks x 512 thr.
// ---------------------------------------------------------------------------
#define DSTR 136
__global__ __launch_bounds__(512) void k_dec_scan(
    const float* __restrict__ dec_Whh, const float* __restrict__ WdecT,
    const int* __restrict__ dec_idx, const float* __restrict__ dh0,
    unsigned short* __restrict__ dhs) {
  __shared__ unsigned short hA[2][16 * DSTR];
  __shared__ int idx_s[4][TOUT];
  int b0 = blockIdx.x * 4;
  int tid = threadIdx.x;
  int w = tid >> 6, lane = tid & 63, n = lane & 15, quad = lane >> 4;
  int j0 = w * 16, j = j0 + n;

  bf16x8 Bf[4][4];
#pragma unroll
  for (int ty = 0; ty < 4; ++ty)
#pragma unroll
    for (int kb = 0; kb < 4; ++kb) {
      const float* src = dec_Whh + (size_t)(ty * 128 + j0 + n) * DHID + kb * 32 + quad * 8;
      Bf[ty][kb] = pack8(*(const float4*)src, *(const float4*)(src + 4));
    }
  for (int i = tid; i < 16 * DSTR; i += 512) {
    int m = i / DSTR, k = i - m * DSTR;
    float v = (k < DHID && (m & 3) == 0) ? dh0[(size_t)(b0 + (m >> 2)) * DHID + k] : 0.0f;
    hA[0][i] = f2bf(v);
    hA[1][i] = 0;
  }
  for (int i = tid; i < 4 * TOUT; i += 512)
    idx_s[i >> 7][i & 127] = dec_idx[(size_t)(b0 + (i >> 7)) * TOUT + (i & 127)];
  __syncthreads();

  float gx[4];
  {
    int id0 = idx_s[quad][0];
#pragma unroll
    for (int ty = 0; ty < 4; ++ty) gx[ty] = WdecT[(size_t)id0 * 512 + ty * 128 + j];
  }
  float c0 = 0.0f;
  for (int t = 0; t < TOUT; ++t) {
    const unsigned short* cur = hA[t & 1];
    bf16x8 a[4];
#pragma unroll
    for (int kb = 0; kb < 4; ++kb)
      a[kb] = *(const bf16x8*)(cur + n * DSTR + kb * 32 + quad * 8);
    float gxn[4];
    int tn = (t + 1 < TOUT) ? t + 1 : t;
    int idn = idx_s[quad][tn];
#pragma unroll
    for (int ty = 0; ty < 4; ++ty) gxn[ty] = WdecT[(size_t)idn * 512 + ty * 128 + j];
    f32x4 acc[4];
#pragma unroll
    for (int ty = 0; ty < 4; ++ty) {
      f32x4 z; z[0] = gx[ty]; z[1] = 0.f; z[2] = 0.f; z[3] = 0.f;
#pragma unroll
      for (int kb = 0; kb < 4; ++kb)
        z = __builtin_amdgcn_mfma_f32_16x16x32_bf16(a[kb], Bf[ty][kb], z, 0, 0, 0);
      acc[ty] = z;
    }
    float gi = acc[0][0], gf = acc[1][0], gg = acc[2][0], go = acc[3][0];
    c0 = sigf(gf) * c0 + sigf(gi) * tanh_(gg);
    float h = sigf(go) * tanh_(c0);
    unsigned short hb = f2bf(h);
    hA[(t + 1) & 1][(quad * 4) * DSTR + j] = hb;
    dhs[((size_t)t * BATCH + b0 + quad) * DHID + j] = hb;
    gx[0] = gxn[0]; gx[1] = gxn[1]; gx[2] = gxn[2]; gx[3] = gxn[3];
    __syncthreads();
  }
}

// ---------------------------------------------------------------------------
// logits[b][t][v] = dhs[t][b][:] . WdT[:][v] + fout[b][v];  f32 store.
// ---------------------------------------------------------------------------
__global__ __launch_bounds__(256) void k_logits(const unsigned short* __restrict__ dhs,
                                                const float* __restrict__ WdT,
                                                const float* __restrict__ fout,
                                                float* __restrict__ out) {
  __shared__ float s[DHID * 64];  // k-major: s[k*64 + m]
  int r0 = blockIdx.x * 64;
  int t = r0 / BATCH;
  int b0 = r0 % BATCH;
  int tid = threadIdx.x;
  for (int i = tid; i < 64 * DHID; i += 256) {
    int m = i >> 7;
    int k = i & 127;
    s[k * 64 + m] = bf2f(dhs[(size_t)(r0 + m) * DHID + k]);
  }
  __syncthreads();
  int v4 = tid & 63;
  int mg = tid >> 6;
  float4 acc[16];
#pragma unroll
  for (int m = 0; m < 16; ++m) acc[m] = make_float4(0.f, 0.f, 0.f, 0.f);
  for (int k = 0; k < DHID; ++k) {
    float4 wv = ((const float4*)(WdT + k * 256))[v4];
    const float4* sk = (const float4*)(s + k * 64 + mg * 16);
#pragma unroll
    for (int jj = 0; jj < 4; ++jj) {
      float4 h4 = sk[jj];
      acc[jj * 4 + 0].x += h4.x * wv.x; acc[jj * 4 + 0].y += h4.x * wv.y;
      acc[jj * 4 + 0].z += h4.x * wv.z; acc[jj * 4 + 0].w += h4.x * wv.w;
      acc[jj * 4 + 1].x += h4.y * wv.x; acc[jj * 4 + 1].y += h4.y * wv.y;
      acc[jj * 4 + 1].z += h4.y * wv.z; acc[jj * 4 + 1].w += h4.y * wv.w;
      acc[jj * 4 + 2].x += h4.z * wv.x; acc[jj * 4 + 2].y += h4.z * wv.y;
      acc[jj * 4 + 2].z += h4.z * wv.z; acc[jj * 4 + 2].w += h4.z * wv.w;
      acc[jj * 4 + 3].x += h4.w * wv.x; acc[jj * 4 + 3].y += h4.w * wv.y;
      acc[jj * 4 + 3].z += h4.w * wv.z; acc[jj * 4 + 3].w += h4.w * wv.w;
    }
  }
#pragma unroll
  for (int m = 0; m < 16; ++m) {
    int bb = b0 + mg * 16 + m;
    float4 fo = ((const float4*)(fout + bb * VOC))[v4];
    float4 r;
    r.x = acc[m].x + fo.x;
    r.y = acc[m].y + fo.y;
    r.z = acc[m].z + fo.z;
    r.w = acc[m].w + fo.w;
    ((float4*)(out + ((size_t)bb * TOUT + t) * VOC))[v4] = r;
  }
}

// ---------------------------------------------------------------------------
extern "C" void kernel_launch(void* const* d_in, const int* in_sizes, int n_in,
                              void* d_out, int out_size, void* d_ws, size_t ws_size,
                              hipStream_t stream) {
  const float* inp_onehot = (const float*)d_in[0];
  const float* zia     = (const float*)d_in[1];
  const float* tgt     = (const float*)d_in[2];
  const float* fortza  = (const float*)d_in[3];
  const float* enc_Wih = (const float*)d_in[4];
  const float* enc_Whh = (const float*)d_in[5];
  const float* enc_b   = (const float*)d_in[6];
  const float* sg_W    = (const float*)d_in[7];
  const float* sg_b    = (const float*)d_in[8];
  const float* Wc_W    = (const float*)d_in[9];
  const float* Wc_b    = (const float*)d_in[10];
  const float* dec_Wih = (const float*)d_in[11];
  const float* dec_Whh = (const float*)d_in[12];
  const float* dec_b   = (const float*)d_in[13];
  const float* out_W   = (const float*)d_in[14];
  const float* out_b   = (const float*)d_in[15];
  float* out = (float*)d_out;

  float* ws = (float*)d_ws;
  int* enc_idx  = (int*)d_ws;              // 131072 ints
  int* dec_idx  = enc_idx + BATCH * TIN;   //  65536 ints
  float* WxT    = ws + 196608;             //  65536 f
  float* WdecT  = ws + 262144;             // 131072 f
  float* WdT    = ws + 393216;             //  32768 f
  float* gxc    = ws + 425984;             // 131072 f
  float* h_enc  = ws + 557056;             //  32768 f
  float* dh0    = ws + 589824;             //  65536 f
  float* fout   = ws + 655360;             // 131072 f
  unsigned short* dhs = (unsigned short*)(ws + 786432);  // 8388608 u16; ~19.9 MB

  // A: WxT prep + gx_const + findidx(enc)
  k_pre<<<192 + BATCH * TIN / 4, 256, 0, stream>>>(
      enc_Wih, enc_b, inp_onehot, zia, WxT, gxc, enc_idx);
  // B: enc scan || WdecT/WdT prep || findidx(dec)
  k_enc_fused<<<288 + BATCH * TOUT / 4, 256, 0, stream>>>(
      enc_Whh, WxT, gxc, enc_idx, h_enc,
      dec_Wih, dec_b, out_W, tgt, WdecT, WdT, dec_idx);
  // C: sg_fortza || dh0
  k_mid<<<576, 256, 0, stream>>>(h_enc, fortza, sg_W, sg_b, out_W, out_b,
                                 zia, Wc_W, Wc_b,
                                 out + (size_t)BATCH * TOUT * VOC, fout, dh0);
  // D: decoder scan
  k_dec_scan<<<BATCH / 4, 512, 0, stream>>>(dec_Whh, WdecT, dec_idx, dh0, dhs);
  // E: logits
  k_logits<<<TOUT * BATCH / 64, 256, 0, stream>>>(dhs, WdT, fout, out);
}

// Round 8
// 539.539 us; speedup vs baseline: 1.2690x; 1.0538x over previous
//
#include <hip/hip_runtime.h>
#include <hip/hip_bf16.h>

#define BATCH 512
#define TIN   256
#define TOUT  128
#define VOC   256
#define NZ    1024
#define EHID  64
#define DHID  128
#define SDIM  32

typedef __attribute__((ext_vector_type(8))) short bf16x8;
typedef __attribute__((ext_vector_type(4))) float f32x4;

__device__ __forceinline__ float bf2f(unsigned short u) {
  return __uint_as_float(((unsigned)u) << 16);
}
__device__ __forceinline__ unsigned short f2bf(float f) {
  unsigned u = __float_as_uint(f);
  u = u + 0x7FFFu + ((u >> 16) & 1u);
  return (unsigned short)(u >> 16);
}
__device__ __forceinline__ float sigf(float x) { return 1.0f / (1.0f + __expf(-x)); }
__device__ __forceinline__ float tanh_(float x) { return 1.0f - 2.0f / (1.0f + __expf(2.0f * x)); }

__device__ __forceinline__ bf16x8 pack8(float4 a, float4 b) {
  bf16x8 r;
  r[0] = (short)f2bf(a.x); r[1] = (short)f2bf(a.y);
  r[2] = (short)f2bf(a.z); r[3] = (short)f2bf(a.w);
  r[4] = (short)f2bf(b.x); r[5] = (short)f2bf(b.y);
  r[6] = (short)f2bf(b.z); r[7] = (short)f2bf(b.w);
  return r;
}

// ---------------------------------------------------------------------------
// findidx worker: one wave, one position (256 f32 one-hot row).
// ---------------------------------------------------------------------------
__device__ __forceinline__ void dev_findidx(const float* __restrict__ src,
                                            int pos, int lane,
                                            int* __restrict__ out) {
  float4 v = ((const float4*)src)[(size_t)pos * 64 + lane];
  int comp = v.x > 0.5f ? 0 : (v.y > 0.5f ? 1 : (v.z > 0.5f ? 2 : 3));
  bool hit = (v.x > 0.5f) || (v.y > 0.5f) || (v.z > 0.5f) || (v.w > 0.5f);
  int cand = hit ? lane * 4 + comp : (1 << 30);
#pragma unroll
  for (int off = 32; off > 0; off >>= 1) {
    int o = __shfl_xor(cand, off);
    cand = cand < o ? cand : o;
  }
  if (lane == 0) out[pos] = cand < VOC ? cand : VOC - 1;
}

// ---------------------------------------------------------------------------
// Launch A: WxT prep (0..63) | gx_const (64..191) | findidx enc (192..2239,
// grid-stride 16 positions/wave).
// ---------------------------------------------------------------------------
__global__ __launch_bounds__(256) void k_pre(
    const float* __restrict__ enc_Wih, const float* __restrict__ enc_b,
    const float* __restrict__ inp_onehot, const float* __restrict__ zia,
    float* __restrict__ WxT, float* __restrict__ gxc, int* __restrict__ enc_idx) {
  int blk = blockIdx.x, tid = threadIdx.x;
  if (blk < 64) {
    __shared__ float T[32][36];
    int r = tid >> 3, c = (tid & 7) * 4;
    int g0 = (blk >> 3) * 32, v0 = (blk & 7) * 32;
    float4 v = *(const float4*)(enc_Wih + (size_t)(g0 + r) * (VOC + NZ) + v0 + c);
    float bias = enc_b[g0 + r];
    T[c + 0][r] = v.x + bias; T[c + 1][r] = v.y + bias;
    T[c + 2][r] = v.z + bias; T[c + 3][r] = v.w + bias;
    __syncthreads();
    *(float4*)(WxT + (size_t)(v0 + r) * 256 + g0 + c) = *(const float4*)&T[r][c];
  } else if (blk < 192) {
    __shared__ float As[32][36], Bs[32][36];
    int q = blk - 64;
    int b0 = (q & 15) * 32, g0 = (q >> 4) * 32;
    int ldr = tid >> 3, ldc = (tid & 7) * 4;
    int tx = tid & 15, ty = tid >> 4;
    float a00 = 0.f, a01 = 0.f, a10 = 0.f, a11 = 0.f;
    for (int kc = 0; kc < NZ; kc += 32) {
      float4 av = *(const float4*)(zia + (size_t)(b0 + ldr) * NZ + kc + ldc);
      float4 bv = *(const float4*)(enc_Wih + (size_t)(g0 + ldr) * (VOC + NZ) + VOC + kc + ldc);
      __syncthreads();
      As[ldc + 0][ldr] = av.x; As[ldc + 1][ldr] = av.y;
      As[ldc + 2][ldr] = av.z; As[ldc + 3][ldr] = av.w;
      Bs[ldc + 0][ldr] = bv.x; Bs[ldc + 1][ldr] = bv.y;
      Bs[ldc + 2][ldr] = bv.z; Bs[ldc + 3][ldr] = bv.w;
      __syncthreads();
#pragma unroll
      for (int k = 0; k < 32; ++k) {
        float x0 = As[k][tx * 2], x1 = As[k][tx * 2 + 1];
        float y0 = Bs[k][ty * 2], y1 = Bs[k][ty * 2 + 1];
        a00 += x0 * y0; a01 += x0 * y1; a10 += x1 * y0; a11 += x1 * y1;
      }
    }
    float* o = gxc + (size_t)(b0 + tx * 2) * 256 + g0 + ty * 2;
    o[0] = a00; o[1] = a01; o[256] = a10; o[257] = a11;
  } else {
    int widx = (blk - 192) * 4 + (tid >> 6);  // 8192 waves
    int lane = tid & 63;
#pragma unroll 2
    for (int i = 0; i < 16; ++i)
      dev_findidx(inp_onehot, widx * 16 + i, lane, enc_idx);
  }
}

// ---------------------------------------------------------------------------
// Launch B: enc_scan (0..127) | WdecT prep (128..255) | WdT prep (256..287) |
// findidx dec (288..543, grid-stride 16/wave).
// ---------------------------------------------------------------------------
#define ESTR 72
__global__ __launch_bounds__(256) void k_enc_fused(
    const float* __restrict__ enc_Whh, const float* __restrict__ WxT,
    const float* __restrict__ gxc, const int* __restrict__ enc_idx,
    float* __restrict__ h_enc,
    const float* __restrict__ dec_Wih, const float* __restrict__ dec_b,
    const float* __restrict__ out_W, const float* __restrict__ tgt,
    float* __restrict__ WdecT, float* __restrict__ WdT, int* __restrict__ dec_idx) {
  int blk = blockIdx.x, tid = threadIdx.x;
  if (blk < 128) {
    __shared__ unsigned short hA[2][16 * ESTR];
    __shared__ int idx_s[4][TIN];
    int b0 = blk * 4;
    int w = tid >> 6, lane = tid & 63, n = lane & 15, quad = lane >> 4;
    int j = w * 16 + n;

    bf16x8 Bf[4][2];
#pragma unroll
    for (int ty = 0; ty < 4; ++ty)
#pragma unroll
      for (int kb = 0; kb < 2; ++kb) {
        const float* s = enc_Whh + (size_t)(ty * 64 + j) * EHID + kb * 32 + quad * 8;
        Bf[ty][kb] = pack8(*(const float4*)s, *(const float4*)(s + 4));
      }
    for (int i = tid; i < 16 * ESTR; i += 256) { hA[0][i] = 0; hA[1][i] = 0; }
    for (int i = tid; i < 4 * TIN; i += 256)
      idx_s[i >> 8][i & 255] = enc_idx[(size_t)(b0 + (i >> 8)) * TIN + (i & 255)];
    float gc[4];
#pragma unroll
    for (int ty = 0; ty < 4; ++ty) gc[ty] = gxc[(size_t)(b0 + quad) * 256 + ty * 64 + j];
    __syncthreads();

    float gx[4];
    {
      int id0 = idx_s[quad][0];
#pragma unroll
      for (int ty = 0; ty < 4; ++ty) gx[ty] = WxT[(size_t)id0 * 256 + ty * 64 + j];
    }
    float c0 = 0.0f, h = 0.0f;
    for (int t = 0; t < TIN; ++t) {
      const unsigned short* cur = hA[t & 1];
      bf16x8 a[2];
#pragma unroll
      for (int kb = 0; kb < 2; ++kb)
        a[kb] = *(const bf16x8*)(cur + n * ESTR + kb * 32 + quad * 8);
      float gxn[4];
      int tn = (t + 1 < TIN) ? t + 1 : t;
      int idn = idx_s[quad][tn];
#pragma unroll
      for (int ty = 0; ty < 4; ++ty) gxn[ty] = WxT[(size_t)idn * 256 + ty * 64 + j];
      f32x4 acc[4];
#pragma unroll
      for (int ty = 0; ty < 4; ++ty) {
        f32x4 z; z[0] = gx[ty] + gc[ty]; z[1] = 0.f; z[2] = 0.f; z[3] = 0.f;
        z = __builtin_amdgcn_mfma_f32_16x16x32_bf16(a[0], Bf[ty][0], z, 0, 0, 0);
        z = __builtin_amdgcn_mfma_f32_16x16x32_bf16(a[1], Bf[ty][1], z, 0, 0, 0);
        acc[ty] = z;
      }
      float gi = acc[0][0], gf = acc[1][0], gg = acc[2][0], go = acc[3][0];
      c0 = sigf(gf) * c0 + sigf(gi) * tanh_(gg);
      h = sigf(go) * tanh_(c0);
      hA[(t + 1) & 1][(quad * 4) * ESTR + j] = f2bf(h);
      gx[0] = gxn[0]; gx[1] = gxn[1]; gx[2] = gxn[2]; gx[3] = gxn[3];
      __syncthreads();
    }
    h_enc[(size_t)(b0 + quad) * EHID + j] = h;
  } else if (blk < 256) {
    __shared__ float T[32][36];
    int q = blk - 128;
    int r = tid >> 3, c = (tid & 7) * 4;
    int g0 = (q >> 3) * 32, v0 = (q & 7) * 32;
    float4 v = *(const float4*)(dec_Wih + (size_t)(g0 + r) * VOC + v0 + c);
    float bias = dec_b[g0 + r];
    T[c + 0][r] = v.x + bias; T[c + 1][r] = v.y + bias;
    T[c + 2][r] = v.z + bias; T[c + 3][r] = v.w + bias;
    __syncthreads();
    *(float4*)(WdecT + (size_t)(v0 + r) * 512 + g0 + c) = *(const float4*)&T[r][c];
  } else if (blk < 288) {
    __shared__ float T2[32][36];
    int q = blk - 256;
    int r = tid >> 3, c = (tid & 7) * 4;
    int v0 = (q >> 2) * 32, k0 = (q & 3) * 32;
    float4 v = *(const float4*)(out_W + (size_t)(v0 + r) * (DHID + SDIM) + k0 + c);
    T2[c + 0][r] = v.x; T2[c + 1][r] = v.y; T2[c + 2][r] = v.z; T2[c + 3][r] = v.w;
    __syncthreads();
    *(float4*)(WdT + (size_t)(k0 + r) * 256 + v0 + c) = *(const float4*)&T2[r][c];
  } else {
    int widx = (blk - 288) * 4 + (tid >> 6);  // 4096 waves
    int lane = tid & 63;
#pragma unroll 2
    for (int i = 0; i < 16; ++i)
      dev_findidx(tgt, widx * 16 + i, lane, dec_idx);
  }
}

// ---------------------------------------------------------------------------
// Launch C: sg_fortza (0..511) | dh0 tiled GEMM (512..575).
// ---------------------------------------------------------------------------
__global__ __launch_bounds__(256) void k_mid(
    const float* __restrict__ h_enc, const float* __restrict__ fortza,
    const float* __restrict__ sg_W, const float* __restrict__ sg_b,
    const float* __restrict__ out_W, const float* __restrict__ out_b,
    const float* __restrict__ zia, const float* __restrict__ Wc_W,
    const float* __restrict__ Wc_b,
    float* __restrict__ out_fortza, float* __restrict__ fout,
    float* __restrict__ dh0) {
  int blk = blockIdx.x, tid = threadIdx.x;
  if (blk < 512) {
    __shared__ float hf[EHID], fz[SDIM], sg_s[2 * SDIM], fn[SDIM];
    int b = blk;
    if (tid < EHID) hf[tid] = h_enc[b * EHID + tid];
    if (tid >= EHID && tid < EHID + SDIM)
      fz[tid - EHID] = fortza[(size_t)b * SDIM + (tid - EHID)];
    __syncthreads();
    if (tid < 2 * SDIM) {
      float acc = sg_b[tid];
      const float* row = sg_W + (size_t)tid * (EHID + SDIM);
      for (int k = 0; k < EHID; ++k) acc += hf[k] * row[k];
      for (int jj = 0; jj < SDIM; ++jj) acc += fz[jj] * row[EHID + jj];
      sg_s[tid] = acc;
    }
    __syncthreads();
    if (tid < SDIM) {
      float gate = sigf(sg_s[tid]);
      float upd = tanh_(sg_s[SDIM + tid]);
      float v = gate * fz[tid] + (1.0f - gate) * upd;
      fn[tid] = v;
      out_fortza[(size_t)b * SDIM + tid] = v;
    }
    __syncthreads();
    {
      float acc = out_b[tid];
      const float* row = out_W + (size_t)tid * (DHID + SDIM) + DHID;
      for (int jj = 0; jj < SDIM; ++jj) acc += fn[jj] * row[jj];
      fout[b * VOC + tid] = acc;
    }
  } else {
    __shared__ float As[32][36], Bs[32][36];
    int q = blk - 512;
    int b0 = (q & 15) * 32, v0 = (q >> 4) * 32;
    int ldr = tid >> 3, ldc = (tid & 7) * 4;
    int tx = tid & 15, ty = tid >> 4;
    float a00 = 0.f, a01 = 0.f, a10 = 0.f, a11 = 0.f;
    for (int kc = 0; kc < EHID + NZ; kc += 32) {
      float4 av;
      if (kc < EHID)
        av = *(const float4*)(h_enc + (size_t)(b0 + ldr) * EHID + kc + ldc);
      else
        av = *(const float4*)(zia + (size_t)(b0 + ldr) * NZ + (kc - EHID) + ldc);
      float4 bv = *(const float4*)(Wc_W + (size_t)(v0 + ldr) * (EHID + NZ) + kc + ldc);
      __syncthreads();
      As[ldc + 0][ldr] = av.x; As[ldc + 1][ldr] = av.y;
      As[ldc + 2][ldr] = av.z; As[ldc + 3][ldr] = av.w;
      Bs[ldc + 0][ldr] = bv.x; Bs[ldc + 1][ldr] = bv.y;
      Bs[ldc + 2][ldr] = bv.z; Bs[ldc + 3][ldr] = bv.w;
      __syncthreads();
#pragma unroll
      for (int k = 0; k < 32; ++k) {
        float x0 = As[k][tx * 2], x1 = As[k][tx * 2 + 1];
        float y0 = Bs[k][ty * 2], y1 = Bs[k][ty * 2 + 1];
        a00 += x0 * y0; a01 += x0 * y1; a10 += x1 * y0; a11 += x1 * y1;
      }
    }
    float bb0 = Wc_b[v0 + ty * 2], bb1 = Wc_b[v0 + ty * 2 + 1];
    float* o = dh0 + (size_t)(b0 + tx * 2) * DHID + v0 + ty * 2;
    o[0] = tanh_(a00 + bb0); o[1] = tanh_(a01 + bb1);
    o[DHID] = tanh_(a10 + bb0); o[DHID + 1] = tanh_(a11 + bb1);
  }
}

// ---------------------------------------------------------------------------
// Launch D: decoder LSTM scan + FUSED logits. 128 blocks x 512 thr (8 waves).
// Scan: 4 batches at A-rows {0,4,8,12}; wave w owns gate j-slice [w*16,+16).
// Logits: wave w also owns vocab tiles {2w, 2w+1}; the scan A-fragment at
// iteration t+1 IS dhs[t], so logits for step t-1 ride on iteration t's a[].
// dhs never touches global memory.
// ---------------------------------------------------------------------------
#define DSTR 136
__global__ __launch_bounds__(512) void k_dec_logits(
    const float* __restrict__ dec_Whh, const float* __restrict__ WdecT,
    const int* __restrict__ dec_idx, const float* __restrict__ dh0,
    const float* __restrict__ WdT, const float* __restrict__ fout,
    float* __restrict__ out) {
  __shared__ unsigned short hA[2][16 * DSTR];
  __shared__ int idx_s[4][TOUT];
  int b0 = blockIdx.x * 4;
  int tid = threadIdx.x;
  int w = tid >> 6, lane = tid & 63, n = lane & 15, quad = lane >> 4;
  int j0 = w * 16, j = j0 + n;

  bf16x8 Bf[4][4];
#pragma unroll
  for (int ty = 0; ty < 4; ++ty)
#pragma unroll
    for (int kb = 0; kb < 4; ++kb) {
      const float* src = dec_Whh + (size_t)(ty * 128 + j0 + n) * DHID + kb * 32 + quad * 8;
      Bf[ty][kb] = pack8(*(const float4*)src, *(const float4*)(src + 4));
    }
  // logits B fragments: vocab tiles 2w, 2w+1; B[k][v] = WdT[k*256+v]
  bf16x8 BfL[2][4];
  float fo[2];
#pragma unroll
  for (int p = 0; p < 2; ++p) {
    int v = (w * 2 + p) * 16 + n;
#pragma unroll
    for (int kb = 0; kb < 4; ++kb) {
      const float* src = WdT + (size_t)(kb * 32 + quad * 8) * 256 + v;
      bf16x8 r;
#pragma unroll
      for (int i = 0; i < 8; ++i) r[i] = (short)f2bf(src[i * 256]);
      BfL[p][kb] = r;
    }
    fo[p] = fout[(size_t)(b0 + quad) * VOC + v];
  }
  for (int i = tid; i < 16 * DSTR; i += 512) {
    int m = i / DSTR, k = i - m * DSTR;
    float v = (k < DHID && (m & 3) == 0) ? dh0[(size_t)(b0 + (m >> 2)) * DHID + k] : 0.0f;
    hA[0][i] = f2bf(v);
    hA[1][i] = 0;
  }
  for (int i = tid; i < 4 * TOUT; i += 512)
    idx_s[i >> 7][i & 127] = dec_idx[(size_t)(b0 + (i >> 7)) * TOUT + (i & 127)];
  __syncthreads();

  float gx[4];
  {
    int id0 = idx_s[quad][0];
#pragma unroll
    for (int ty = 0; ty < 4; ++ty) gx[ty] = WdecT[(size_t)id0 * 512 + ty * 128 + j];
  }
  float c0 = 0.0f;
  for (int t = 0; t < TOUT; ++t) {
    const unsigned short* cur = hA[t & 1];
    bf16x8 a[4];
#pragma unroll
    for (int kb = 0; kb < 4; ++kb)
      a[kb] = *(const bf16x8*)(cur + n * DSTR + kb * 32 + quad * 8);
    // fused logits for output step t-1 (a[] = dhs[t-1])
    if (t > 0) {
#pragma unroll
      for (int p = 0; p < 2; ++p) {
        f32x4 z; z[0] = fo[p]; z[1] = 0.f; z[2] = 0.f; z[3] = 0.f;
#pragma unroll
        for (int kb = 0; kb < 4; ++kb)
          z = __builtin_amdgcn_mfma_f32_16x16x32_bf16(a[kb], BfL[p][kb], z, 0, 0, 0);
        out[((size_t)(b0 + quad) * TOUT + (t - 1)) * VOC + (w * 2 + p) * 16 + n] = z[0];
      }
    }
    float gxn[4];
    int tn = (t + 1 < TOUT) ? t + 1 : t;
    int idn = idx_s[quad][tn];
#pragma unroll
    for (int ty = 0; ty < 4; ++ty) gxn[ty] = WdecT[(size_t)idn * 512 + ty * 128 + j];
    f32x4 acc[4];
#pragma unroll
    for (int ty = 0; ty < 4; ++ty) {
      f32x4 z; z[0] = gx[ty]; z[1] = 0.f; z[2] = 0.f; z[3] = 0.f;
#pragma unroll
      for (int kb = 0; kb < 4; ++kb)
        z = __builtin_amdgcn_mfma_f32_16x16x32_bf16(a[kb], Bf[ty][kb], z, 0, 0, 0);
      acc[ty] = z;
    }
    float gi = acc[0][0], gf = acc[1][0], gg = acc[2][0], go = acc[3][0];
    c0 = sigf(gf) * c0 + sigf(gi) * tanh_(gg);
    float h = sigf(go) * tanh_(c0);
    hA[(t + 1) & 1][(quad * 4) * DSTR + j] = f2bf(h);
    gx[0] = gxn[0]; gx[1] = gxn[1]; gx[2] = gxn[2]; gx[3] = gxn[3];
    __syncthreads();
  }
  // epilogue: logits for t = TOUT-1 from h_TOUT (in hA[0] since TOUT is even)
  {
    const unsigned short* cur = hA[0];
    bf16x8 a[4];
#pragma unroll
    for (int kb = 0; kb < 4; ++kb)
      a[kb] = *(const bf16x8*)(cur + n * DSTR + kb * 32 + quad * 8);
#pragma unroll
    for (int p = 0; p < 2; ++p) {
      f32x4 z; z[0] = fo[p]; z[1] = 0.f; z[2] = 0.f; z[3] = 0.f;
#pragma unroll
      for (int kb = 0; kb < 4; ++kb)
        z = __builtin_amdgcn_mfma_f32_16x16x32_bf16(a[kb], BfL[p][kb], z, 0, 0, 0);
      out[((size_t)(b0 + quad) * TOUT + (TOUT - 1)) * VOC + (w * 2 + p) * 16 + n] = z[0];
    }
  }
}

// ---------------------------------------------------------------------------
extern "C" void kernel_launch(void* const* d_in, const int* in_sizes, int n_in,
                              void* d_out, int out_size, void* d_ws, size_t ws_size,
                              hipStream_t stream) {
  const float* inp_onehot = (const float*)d_in[0];
  const float* zia     = (const float*)d_in[1];
  const float* tgt     = (const float*)d_in[2];
  const float* fortza  = (const float*)d_in[3];
  const float* enc_Wih = (const float*)d_in[4];
  const float* enc_Whh = (const float*)d_in[5];
  const float* enc_b   = (const float*)d_in[6];
  const float* sg_W    = (const float*)d_in[7];
  const float* sg_b    = (const float*)d_in[8];
  const float* Wc_W    = (const float*)d_in[9];
  const float* Wc_b    = (const float*)d_in[10];
  const float* dec_Wih = (const float*)d_in[11];
  const float* dec_Whh = (const float*)d_in[12];
  const float* dec_b   = (const float*)d_in[13];
  const float* out_W   = (const float*)d_in[14];
  const float* out_b   = (const float*)d_in[15];
  float* out = (float*)d_out;

  float* ws = (float*)d_ws;
  int* enc_idx  = (int*)d_ws;              // 131072 ints
  int* dec_idx  = enc_idx + BATCH * TIN;   //  65536 ints
  float* WxT    = ws + 196608;             //  65536 f
  float* WdecT  = ws + 262144;             // 131072 f
  float* WdT    = ws + 393216;             //  32768 f
  float* gxc    = ws + 425984;             // 131072 f
  float* h_enc  = ws + 557056;             //  32768 f
  float* dh0    = ws + 589824;             //  65536 f
  float* fout   = ws + 655360;             // 131072 f  (ends 786432 f ≈ 3.1 MB)

  // A: WxT prep + gx_const + findidx(enc)
  k_pre<<<192 + 2048, 256, 0, stream>>>(
      enc_Wih, enc_b, inp_onehot, zia, WxT, gxc, enc_idx);
  // B: enc scan || WdecT/WdT prep || findidx(dec)
  k_enc_fused<<<288 + 1024, 256, 0, stream>>>(
      enc_Whh, WxT, gxc, enc_idx, h_enc,
      dec_Wih, dec_b, out_W, tgt, WdecT, WdT, dec_idx);
  // C: sg_fortza || dh0
  k_mid<<<576, 256, 0, stream>>>(h_enc, fortza, sg_W, sg_b, out_W, out_b,
                                 zia, Wc_W, Wc_b,
                                 out + (size_t)BATCH * TOUT * VOC, fout, dh0);
  // D: decoder scan + fused logits
  k_dec_logits<<<BATCH / 4, 512, 0, stream>>>(dec_Whh, WdecT, dec_idx, dh0,
                                              WdT, fout, out);
}

// Round 9
// 534.887 us; speedup vs baseline: 1.2800x; 1.0087x over previous
//
#include <hip/hip_runtime.h>
#include <hip/hip_bf16.h>

#define BATCH 512
#define TIN   256
#define TOUT  128
#define VOC   256
#define NZ    1024
#define EHID  64
#define DHID  128
#define SDIM  32

typedef __attribute__((ext_vector_type(8))) short bf16x8;
typedef __attribute__((ext_vector_type(4))) float f32x4;

__device__ __forceinline__ float bf2f(unsigned short u) {
  return __uint_as_float(((unsigned)u) << 16);
}
__device__ __forceinline__ unsigned short f2bf(float f) {
  unsigned u = __float_as_uint(f);
  u = u + 0x7FFFu + ((u >> 16) & 1u);
  return (unsigned short)(u >> 16);
}
__device__ __forceinline__ float sigf(float x) { return 1.0f / (1.0f + __expf(-x)); }
__device__ __forceinline__ float tanh_(float x) { return 1.0f - 2.0f / (1.0f + __expf(2.0f * x)); }

// Block barrier that drains ONLY LDS counters (no vmcnt drain) — in-flight
// global loads/stores stay queued across the barrier; the compiler's own
// vmcnt(N) waits at use sites handle data deps. This removes the per-step
// s_waitcnt vmcnt(0) stall that __syncthreads() forces.
__device__ __forceinline__ void sync_lds() {
  asm volatile("s_waitcnt lgkmcnt(0)\n\ts_barrier" ::: "memory");
}

__device__ __forceinline__ bf16x8 pack8(float4 a, float4 b) {
  bf16x8 r;
  r[0] = (short)f2bf(a.x); r[1] = (short)f2bf(a.y);
  r[2] = (short)f2bf(a.z); r[3] = (short)f2bf(a.w);
  r[4] = (short)f2bf(b.x); r[5] = (short)f2bf(b.y);
  r[6] = (short)f2bf(b.z); r[7] = (short)f2bf(b.w);
  return r;
}

// ---------------------------------------------------------------------------
// findidx worker: one wave, one position (256 f32 one-hot row).
// ---------------------------------------------------------------------------
__device__ __forceinline__ void dev_findidx(const float* __restrict__ src,
                                            int pos, int lane,
                                            int* __restrict__ out) {
  float4 v = ((const float4*)src)[(size_t)pos * 64 + lane];
  int comp = v.x > 0.5f ? 0 : (v.y > 0.5f ? 1 : (v.z > 0.5f ? 2 : 3));
  bool hit = (v.x > 0.5f) || (v.y > 0.5f) || (v.z > 0.5f) || (v.w > 0.5f);
  int cand = hit ? lane * 4 + comp : (1 << 30);
#pragma unroll
  for (int off = 32; off > 0; off >>= 1) {
    int o = __shfl_xor(cand, off);
    cand = cand < o ? cand : o;
  }
  if (lane == 0) out[pos] = cand < VOC ? cand : VOC - 1;
}

// ---------------------------------------------------------------------------
// Launch A: WxT prep (0..63) | gx_const (64..191) | findidx enc (192..2239).
// ---------------------------------------------------------------------------
__global__ __launch_bounds__(256) void k_pre(
    const float* __restrict__ enc_Wih, const float* __restrict__ enc_b,
    const float* __restrict__ inp_onehot, const float* __restrict__ zia,
    float* __restrict__ WxT, float* __restrict__ gxc, int* __restrict__ enc_idx) {
  int blk = blockIdx.x, tid = threadIdx.x;
  if (blk < 64) {
    __shared__ float T[32][36];
    int r = tid >> 3, c = (tid & 7) * 4;
    int g0 = (blk >> 3) * 32, v0 = (blk & 7) * 32;
    float4 v = *(const float4*)(enc_Wih + (size_t)(g0 + r) * (VOC + NZ) + v0 + c);
    float bias = enc_b[g0 + r];
    T[c + 0][r] = v.x + bias; T[c + 1][r] = v.y + bias;
    T[c + 2][r] = v.z + bias; T[c + 3][r] = v.w + bias;
    __syncthreads();
    *(float4*)(WxT + (size_t)(v0 + r) * 256 + g0 + c) = *(const float4*)&T[r][c];
  } else if (blk < 192) {
    __shared__ float As[32][36], Bs[32][36];
    int q = blk - 64;
    int b0 = (q & 15) * 32, g0 = (q >> 4) * 32;
    int ldr = tid >> 3, ldc = (tid & 7) * 4;
    int tx = tid & 15, ty = tid >> 4;
    float a00 = 0.f, a01 = 0.f, a10 = 0.f, a11 = 0.f;
    for (int kc = 0; kc < NZ; kc += 32) {
      float4 av = *(const float4*)(zia + (size_t)(b0 + ldr) * NZ + kc + ldc);
      float4 bv = *(const float4*)(enc_Wih + (size_t)(g0 + ldr) * (VOC + NZ) + VOC + kc + ldc);
      __syncthreads();
      As[ldc + 0][ldr] = av.x; As[ldc + 1][ldr] = av.y;
      As[ldc + 2][ldr] = av.z; As[ldc + 3][ldr] = av.w;
      Bs[ldc + 0][ldr] = bv.x; Bs[ldc + 1][ldr] = bv.y;
      Bs[ldc + 2][ldr] = bv.z; Bs[ldc + 3][ldr] = bv.w;
      __syncthreads();
#pragma unroll
      for (int k = 0; k < 32; ++k) {
        float x0 = As[k][tx * 2], x1 = As[k][tx * 2 + 1];
        float y0 = Bs[k][ty * 2], y1 = Bs[k][ty * 2 + 1];
        a00 += x0 * y0; a01 += x0 * y1; a10 += x1 * y0; a11 += x1 * y1;
      }
    }
    float* o = gxc + (size_t)(b0 + tx * 2) * 256 + g0 + ty * 2;
    o[0] = a00; o[1] = a01; o[256] = a10; o[257] = a11;
  } else {
    int widx = (blk - 192) * 4 + (tid >> 6);  // 8192 waves
    int lane = tid & 63;
#pragma unroll 2
    for (int i = 0; i < 16; ++i)
      dev_findidx(inp_onehot, widx * 16 + i, lane, enc_idx);
  }
}

// ---------------------------------------------------------------------------
// Launch B: enc_scan (0..127) | WdecT prep (128..255) | WdT prep (256..287) |
// findidx dec (288..543).
// ---------------------------------------------------------------------------
#define ESTR 72
__global__ __launch_bounds__(256) void k_enc_fused(
    const float* __restrict__ enc_Whh, const float* __restrict__ WxT,
    const float* __restrict__ gxc, const int* __restrict__ enc_idx,
    float* __restrict__ h_enc,
    const float* __restrict__ dec_Wih, const float* __restrict__ dec_b,
    const float* __restrict__ out_W, const float* __restrict__ tgt,
    float* __restrict__ WdecT, float* __restrict__ WdT, int* __restrict__ dec_idx) {
  int blk = blockIdx.x, tid = threadIdx.x;
  if (blk < 128) {
    __shared__ unsigned short hA[2][16 * ESTR];
    __shared__ int idx_s[4][TIN];
    int b0 = blk * 4;
    int w = tid >> 6, lane = tid & 63, n = lane & 15, quad = lane >> 4;
    int j = w * 16 + n;

    bf16x8 Bf[4][2];
#pragma unroll
    for (int ty = 0; ty < 4; ++ty)
#pragma unroll
      for (int kb = 0; kb < 2; ++kb) {
        const float* s = enc_Whh + (size_t)(ty * 64 + j) * EHID + kb * 32 + quad * 8;
        Bf[ty][kb] = pack8(*(const float4*)s, *(const float4*)(s + 4));
      }
    for (int i = tid; i < 16 * ESTR; i += 256) { hA[0][i] = 0; hA[1][i] = 0; }
    for (int i = tid; i < 4 * TIN; i += 256)
      idx_s[i >> 8][i & 255] = enc_idx[(size_t)(b0 + (i >> 8)) * TIN + (i & 255)];
    float gc[4];
#pragma unroll
    for (int ty = 0; ty < 4; ++ty) gc[ty] = gxc[(size_t)(b0 + quad) * 256 + ty * 64 + j];
    __syncthreads();

    float gx[4];
    {
      int id0 = idx_s[quad][0];
#pragma unroll
      for (int ty = 0; ty < 4; ++ty) gx[ty] = WxT[(size_t)id0 * 256 + ty * 64 + j];
    }
    float c0 = 0.0f, h = 0.0f;
    for (int t = 0; t < TIN; ++t) {
      const unsigned short* cur = hA[t & 1];
      bf16x8 a[2];
#pragma unroll
      for (int kb = 0; kb < 2; ++kb)
        a[kb] = *(const bf16x8*)(cur + n * ESTR + kb * 32 + quad * 8);
      float gxn[4];
      int tn = (t + 1 < TIN) ? t + 1 : t;
      int idn = idx_s[quad][tn];
#pragma unroll
      for (int ty = 0; ty < 4; ++ty) gxn[ty] = WxT[(size_t)idn * 256 + ty * 64 + j];
      f32x4 acc[4];
#pragma unroll
      for (int ty = 0; ty < 4; ++ty) {
        f32x4 z; z[0] = gx[ty] + gc[ty]; z[1] = 0.f; z[2] = 0.f; z[3] = 0.f;
        z = __builtin_amdgcn_mfma_f32_16x16x32_bf16(a[0], Bf[ty][0], z, 0, 0, 0);
        z = __builtin_amdgcn_mfma_f32_16x16x32_bf16(a[1], Bf[ty][1], z, 0, 0, 0);
        acc[ty] = z;
      }
      float gi = acc[0][0], gf = acc[1][0], gg = acc[2][0], go = acc[3][0];
      c0 = sigf(gf) * c0 + sigf(gi) * tanh_(gg);
      h = sigf(go) * tanh_(c0);
      hA[(t + 1) & 1][(quad * 4) * ESTR + j] = f2bf(h);
      gx[0] = gxn[0]; gx[1] = gxn[1]; gx[2] = gxn[2]; gx[3] = gxn[3];
      sync_lds();  // lgkm-only barrier: WxT prefetch stays in flight
    }
    h_enc[(size_t)(b0 + quad) * EHID + j] = h;
  } else if (blk < 256) {
    __shared__ float T[32][36];
    int q = blk - 128;
    int r = tid >> 3, c = (tid & 7) * 4;
    int g0 = (q >> 3) * 32, v0 = (q & 7) * 32;
    float4 v = *(const float4*)(dec_Wih + (size_t)(g0 + r) * VOC + v0 + c);
    float bias = dec_b[g0 + r];
    T[c + 0][r] = v.x + bias; T[c + 1][r] = v.y + bias;
    T[c + 2][r] = v.z + bias; T[c + 3][r] = v.w + bias;
    __syncthreads();
    *(float4*)(WdecT + (size_t)(v0 + r) * 512 + g0 + c) = *(const float4*)&T[r][c];
  } else if (blk < 288) {
    __shared__ float T2[32][36];
    int q = blk - 256;
    int r = tid >> 3, c = (tid & 7) * 4;
    int v0 = (q >> 2) * 32, k0 = (q & 3) * 32;
    float4 v = *(const float4*)(out_W + (size_t)(v0 + r) * (DHID + SDIM) + k0 + c);
    T2[c + 0][r] = v.x; T2[c + 1][r] = v.y; T2[c + 2][r] = v.z; T2[c + 3][r] = v.w;
    __syncthreads();
    *(float4*)(WdT + (size_t)(k0 + r) * 256 + v0 + c) = *(const float4*)&T2[r][c];
  } else {
    int widx = (blk - 288) * 4 + (tid >> 6);  // 4096 waves
    int lane = tid & 63;
#pragma unroll 2
    for (int i = 0; i < 16; ++i)
      dev_findidx(tgt, widx * 16 + i, lane, dec_idx);
  }
}

// ---------------------------------------------------------------------------
// Launch C: sg_fortza (0..511) | dh0 tiled GEMM (512..575).
// ---------------------------------------------------------------------------
__global__ __launch_bounds__(256) void k_mid(
    const float* __restrict__ h_enc, const float* __restrict__ fortza,
    const float* __restrict__ sg_W, const float* __restrict__ sg_b,
    const float* __restrict__ out_W, const float* __restrict__ out_b,
    const float* __restrict__ zia, const float* __restrict__ Wc_W,
    const float* __restrict__ Wc_b,
    float* __restrict__ out_fortza, float* __restrict__ fout,
    float* __restrict__ dh0) {
  int blk = blockIdx.x, tid = threadIdx.x;
  if (blk < 512) {
    __shared__ float hf[EHID], fz[SDIM], sg_s[2 * SDIM], fn[SDIM];
    int b = blk;
    if (tid < EHID) hf[tid] = h_enc[b * EHID + tid];
    if (tid >= EHID && tid < EHID + SDIM)
      fz[tid - EHID] = fortza[(size_t)b * SDIM + (tid - EHID)];
    __syncthreads();
    if (tid < 2 * SDIM) {
      float acc = sg_b[tid];
      const float* row = sg_W + (size_t)tid * (EHID + SDIM);
      for (int k = 0; k < EHID; ++k) acc += hf[k] * row[k];
      for (int jj = 0; jj < SDIM; ++jj) acc += fz[jj] * row[EHID + jj];
      sg_s[tid] = acc;
    }
    __syncthreads();
    if (tid < SDIM) {
      float gate = sigf(sg_s[tid]);
      float upd = tanh_(sg_s[SDIM + tid]);
      float v = gate * fz[tid] + (1.0f - gate) * upd;
      fn[tid] = v;
      out_fortza[(size_t)b * SDIM + tid] = v;
    }
    __syncthreads();
    {
      float acc = out_b[tid];
      const float* row = out_W + (size_t)tid * (DHID + SDIM) + DHID;
      for (int jj = 0; jj < SDIM; ++jj) acc += fn[jj] * row[jj];
      fout[b * VOC + tid] = acc;
    }
  } else {
    __shared__ float As[32][36], Bs[32][36];
    int q = blk - 512;
    int b0 = (q & 15) * 32, v0 = (q >> 4) * 32;
    int ldr = tid >> 3, ldc = (tid & 7) * 4;
    int tx = tid & 15, ty = tid >> 4;
    float a00 = 0.f, a01 = 0.f, a10 = 0.f, a11 = 0.f;
    for (int kc = 0; kc < EHID + NZ; kc += 32) {
      float4 av;
      if (kc < EHID)
        av = *(const float4*)(h_enc + (size_t)(b0 + ldr) * EHID + kc + ldc);
      else
        av = *(const float4*)(zia + (size_t)(b0 + ldr) * NZ + (kc - EHID) + ldc);
      float4 bv = *(const float4*)(Wc_W + (size_t)(v0 + ldr) * (EHID + NZ) + kc + ldc);
      __syncthreads();
      As[ldc + 0][ldr] = av.x; As[ldc + 1][ldr] = av.y;
      As[ldc + 2][ldr] = av.z; As[ldc + 3][ldr] = av.w;
      Bs[ldc + 0][ldr] = bv.x; Bs[ldc + 1][ldr] = bv.y;
      Bs[ldc + 2][ldr] = bv.z; Bs[ldc + 3][ldr] = bv.w;
      __syncthreads();
#pragma unroll
      for (int k = 0; k < 32; ++k) {
        float x0 = As[k][tx * 2], x1 = As[k][tx * 2 + 1];
        float y0 = Bs[k][ty * 2], y1 = Bs[k][ty * 2 + 1];
        a00 += x0 * y0; a01 += x0 * y1; a10 += x1 * y0; a11 += x1 * y1;
      }
    }
    float bb0 = Wc_b[v0 + ty * 2], bb1 = Wc_b[v0 + ty * 2 + 1];
    float* o = dh0 + (size_t)(b0 + tx * 2) * DHID + v0 + ty * 2;
    o[0] = tanh_(a00 + bb0); o[1] = tanh_(a01 + bb1);
    o[DHID] = tanh_(a10 + bb0); o[DHID + 1] = tanh_(a11 + bb1);
  }
}

// ---------------------------------------------------------------------------
// Launch D: decoder LSTM scan + fused logits. 128 blocks x 512 thr (8 waves).
// Logits for step t-1 ride on iteration t's a[] fragment (a[] = dhs[t-1]).
// ---------------------------------------------------------------------------
#define DSTR 136
__global__ __launch_bounds__(512) void k_dec_logits(
    const float* __restrict__ dec_Whh, const float* __restrict__ WdecT,
    const int* __restrict__ dec_idx, const float* __restrict__ dh0,
    const float* __restrict__ WdT, const float* __restrict__ fout,
    float* __restrict__ out) {
  __shared__ unsigned short hA[2][16 * DSTR];
  __shared__ int idx_s[4][TOUT];
  int b0 = blockIdx.x * 4;
  int tid = threadIdx.x;
  int w = tid >> 6, lane = tid & 63, n = lane & 15, quad = lane >> 4;
  int j0 = w * 16, j = j0 + n;

  bf16x8 Bf[4][4];
#pragma unroll
  for (int ty = 0; ty < 4; ++ty)
#pragma unroll
    for (int kb = 0; kb < 4; ++kb) {
      const float* src = dec_Whh + (size_t)(ty * 128 + j0 + n) * DHID + kb * 32 + quad * 8;
      Bf[ty][kb] = pack8(*(const float4*)src, *(const float4*)(src + 4));
    }
  bf16x8 BfL[2][4];
  float fo[2];
  float* op[2];
#pragma unroll
  for (int p = 0; p < 2; ++p) {
    int v = (w * 2 + p) * 16 + n;
#pragma unroll
    for (int kb = 0; kb < 4; ++kb) {
      const float* src = WdT + (size_t)(kb * 32 + quad * 8) * 256 + v;
      bf16x8 r;
#pragma unroll
      for (int i = 0; i < 8; ++i) r[i] = (short)f2bf(src[i * 256]);
      BfL[p][kb] = r;
    }
    fo[p] = fout[(size_t)(b0 + quad) * VOC + v];
    op[p] = out + (size_t)(b0 + quad) * TOUT * VOC + v;  // += VOC each step
  }
  for (int i = tid; i < 16 * DSTR; i += 512) {
    int m = i / DSTR, k = i - m * DSTR;
    float v = (k < DHID && (m & 3) == 0) ? dh0[(size_t)(b0 + (m >> 2)) * DHID + k] : 0.0f;
    hA[0][i] = f2bf(v);
    hA[1][i] = 0;
  }
  for (int i = tid; i < 4 * TOUT; i += 512)
    idx_s[i >> 7][i & 127] = dec_idx[(size_t)(b0 + (i >> 7)) * TOUT + (i & 127)];
  __syncthreads();

  float gx[4];
  {
    int id0 = idx_s[quad][0];
#pragma unroll
    for (int ty = 0; ty < 4; ++ty) gx[ty] = WdecT[(size_t)id0 * 512 + ty * 128 + j];
  }
  float c0 = 0.0f;
  for (int t = 0; t < TOUT; ++t) {
    const unsigned short* cur = hA[t & 1];
    bf16x8 a[4];
#pragma unroll
    for (int kb = 0; kb < 4; ++kb)
      a[kb] = *(const bf16x8*)(cur + n * DSTR + kb * 32 + quad * 8);
    float gxn[4];
    int tn = (t + 1 < TOUT) ? t + 1 : t;
    int idn = idx_s[quad][tn];
#pragma unroll
    for (int ty = 0; ty < 4; ++ty) gxn[ty] = WdecT[(size_t)idn * 512 + ty * 128 + j];
    // scan MFMAs (critical path) first
    f32x4 acc[4];
#pragma unroll
    for (int ty = 0; ty < 4; ++ty) {
      f32x4 z; z[0] = gx[ty]; z[1] = 0.f; z[2] = 0.f; z[3] = 0.f;
#pragma unroll
      for (int kb = 0; kb < 4; ++kb)
        z = __builtin_amdgcn_mfma_f32_16x16x32_bf16(a[kb], Bf[ty][kb], z, 0, 0, 0);
      acc[ty] = z;
    }
    float gi = acc[0][0], gf = acc[1][0], gg = acc[2][0], go = acc[3][0];
    c0 = sigf(gf) * c0 + sigf(gi) * tanh_(gg);
    float h = sigf(go) * tanh_(c0);
    hA[(t + 1) & 1][(quad * 4) * DSTR + j] = f2bf(h);
    // fused logits for step t-1 (latency-tolerant; stores ride past barrier)
    if (t > 0) {
#pragma unroll
      for (int p = 0; p < 2; ++p) {
        f32x4 z; z[0] = fo[p]; z[1] = 0.f; z[2] = 0.f; z[3] = 0.f;
#pragma unroll
        for (int kb = 0; kb < 4; ++kb)
          z = __builtin_amdgcn_mfma_f32_16x16x32_bf16(a[kb], BfL[p][kb], z, 0, 0, 0);
        *op[p] = z[0];
        op[p] += VOC;
      }
    }
    gx[0] = gxn[0]; gx[1] = gxn[1]; gx[2] = gxn[2]; gx[3] = gxn[3];
    sync_lds();  // lgkm-only barrier: loads/stores stay in flight
  }
  // epilogue: logits for t = TOUT-1 from h_TOUT (in hA[0], TOUT even)
  {
    const unsigned short* cur = hA[0];
    bf16x8 a[4];
#pragma unroll
    for (int kb = 0; kb < 4; ++kb)
      a[kb] = *(const bf16x8*)(cur + n * DSTR + kb * 32 + quad * 8);
#pragma unroll
    for (int p = 0; p < 2; ++p) {
      f32x4 z; z[0] = fo[p]; z[1] = 0.f; z[2] = 0.f; z[3] = 0.f;
#pragma unroll
      for (int kb = 0; kb < 4; ++kb)
        z = __builtin_amdgcn_mfma_f32_16x16x32_bf16(a[kb], BfL[p][kb], z, 0, 0, 0);
      *op[p] = z[0];
    }
  }
}

// ---------------------------------------------------------------------------
extern "C" void kernel_launch(void* const* d_in, const int* in_sizes, int n_in,
                              void* d_out, int out_size, void* d_ws, size_t ws_size,
                              hipStream_t stream) {
  const float* inp_onehot = (const float*)d_in[0];
  const float* zia     = (const float*)d_in[1];
  const float* tgt     = (const float*)d_in[2];
  const float* fortza  = (const float*)d_in[3];
  const float* enc_Wih = (const float*)d_in[4];
  const float* enc_Whh = (const float*)d_in[5];
  const float* enc_b   = (const float*)d_in[6];
  const float* sg_W    = (const float*)d_in[7];
  const float* sg_b    = (const float*)d_in[8];
  const float* Wc_W    = (const float*)d_in[9];
  const float* Wc_b    = (const float*)d_in[10];
  const float* dec_Wih = (const float*)d_in[11];
  const float* dec_Whh = (const float*)d_in[12];
  const float* dec_b   = (const float*)d_in[13];
  const float* out_W   = (const float*)d_in[14];
  const float* out_b   = (const float*)d_in[15];
  float* out = (float*)d_out;

  float* ws = (float*)d_ws;
  int* enc_idx  = (int*)d_ws;              // 131072 ints
  int* dec_idx  = enc_idx + BATCH * TIN;   //  65536 ints
  float* WxT    = ws + 196608;             //  65536 f
  float* WdecT  = ws + 262144;             // 131072 f
  float* WdT    = ws + 393216;             //  32768 f
  float* gxc    = ws + 425984;             // 131072 f
  float* h_enc  = ws + 557056;             //  32768 f
  float* dh0    = ws + 589824;             //  65536 f
  float* fout   = ws + 655360;             // 131072 f  (~3.1 MB total)

  k_pre<<<192 + 2048, 256, 0, stream>>>(
      enc_Wih, enc_b, inp_onehot, zia, WxT, gxc, enc_idx);
  k_enc_fused<<<288 + 1024, 256, 0, stream>>>(
      enc_Whh, WxT, gxc, enc_idx, h_enc,
      dec_Wih, dec_b, out_W, tgt, WdecT, WdT, dec_idx);
  k_mid<<<576, 256, 0, stream>>>(h_enc, fortza, sg_W, sg_b, out_W, out_b,
                                 zia, Wc_W, Wc_b,
                                 out + (size_t)BATCH * TOUT * VOC, fout, dh0);
  k_dec_logits<<<BATCH / 4, 512, 0, stream>>>(dec_Whh, WdecT, dec_idx, dh0,
                                              WdT, fout, out);
}